// Round 1
// baseline (260.853 us; speedup 1.0000x reference)
//
#include <hip/hip_runtime.h>
#include <stdint.h>

typedef short bf16x8 __attribute__((ext_vector_type(8)));
typedef float f32x4 __attribute__((ext_vector_type(4)));

#define DEV __device__ __forceinline__

static constexpr int BB = 2, NN = 2048, DD = 1024, HH = 16, DH = 64;
static constexpr float SCALE = 0.125f; // DH^-0.5

// ---- workspace layout (bytes) ----
static constexpr size_t OFF_PACK   = 1024;
static constexpr size_t PACK_WORDS = (size_t)BB * NN * (NN / 64);  // 131072 u64 = 1MB
static constexpr size_t OFF_WT     = OFF_PACK + PACK_WORDS * 8;
static constexpr size_t WT_ONE     = (size_t)DD * DD;              // elements per W
static constexpr size_t OFF_QH     = OFF_WT + 4 * WT_ONE * 2;
static constexpr size_t HEAD_ELEMS = (size_t)BB * HH * NN * DH;    // 4M elems
static constexpr size_t OFF_KH     = OFF_QH + HEAD_ELEMS * 2;
static constexpr size_t OFF_VH     = OFF_KH + HEAD_ELEMS * 2;
static constexpr size_t OFF_VT     = OFF_VH + HEAD_ELEMS * 2;
static constexpr size_t OFF_X      = OFF_VT + HEAD_ELEMS * 2;
// total ~51.4MB of d_ws

DEV unsigned short f2b(float f) {                  // fp32 -> bf16 RNE
  unsigned int u = __builtin_bit_cast(unsigned int, f);
  u = (u + 0x7fffu + ((u >> 16) & 1u)) >> 16;
  return (unsigned short)u;
}

// ---------------- mask dtype detection ----------------
// Classify first 4KB: int32 {0,1} / float32 {0,1.0f} / uint8 {0,1} packed.
__global__ void detect_mask(const unsigned int* m, unsigned int* flag) {
  int t = threadIdx.x;
  uint4 v = ((const uint4*)m)[t];                 // 256*16B = 4KB (mask buf >= 8MB)
  unsigned int vals[4] = {v.x, v.y, v.z, v.w};
  unsigned int f = 0;
  for (int i = 0; i < 4; i++) {
    unsigned int x = vals[i];
    if (x != 0u && x != 1u) f |= 1u;              // not int32-{0,1}
    if (x != 0u && x != 0x3f800000u) f |= 2u;     // not f32-{0,1.0}
  }
  if (f) atomicOr(flag, f);
}

// ---------------- mask packing: 1 bit per entry ----------------
__global__ void pack_mask(const void* msrc, const unsigned int* flag,
                          unsigned long long* packed) {
  int w = blockIdx.x * 256 + threadIdx.x;         // 0..131071
  unsigned int f = *flag;
  size_t base = (size_t)(w >> 5) * 2048 + (size_t)(w & 31) * 64; // element idx
  unsigned long long bits = 0ull;
  if (!(f & 1u)) {                                 // int32 storage
    const int4* p = (const int4*)msrc + (base >> 2);
    #pragma unroll
    for (int c = 0; c < 16; c++) {
      int4 q = p[c];
      if (q.x) bits |= 1ull << (4 * c + 0);
      if (q.y) bits |= 1ull << (4 * c + 1);
      if (q.z) bits |= 1ull << (4 * c + 2);
      if (q.w) bits |= 1ull << (4 * c + 3);
    }
  } else if (!(f & 2u)) {                          // float32 storage
    const float4* p = (const float4*)msrc + (base >> 2);
    #pragma unroll
    for (int c = 0; c < 16; c++) {
      float4 q = p[c];
      if (q.x != 0.f) bits |= 1ull << (4 * c + 0);
      if (q.y != 0.f) bits |= 1ull << (4 * c + 1);
      if (q.z != 0.f) bits |= 1ull << (4 * c + 2);
      if (q.w != 0.f) bits |= 1ull << (4 * c + 3);
    }
  } else {                                         // uint8/bool storage
    const uint4* p = (const uint4*)((const char*)msrc + base);
    #pragma unroll
    for (int c = 0; c < 4; c++) {
      uint4 q = p[c];
      unsigned int vals[4] = {q.x, q.y, q.z, q.w};
      #pragma unroll
      for (int i = 0; i < 4; i++)
        #pragma unroll
        for (int j = 0; j < 4; j++)
          if ((vals[i] >> (8 * j)) & 0xffu) bits |= 1ull << (16 * c + 4 * i + j);
    }
  }
  packed[w] = bits;
}

// ---------------- weight transpose: W[k][n] f32 -> Wt[n][k] bf16 ----------------
__global__ void transpose_w(const float* W0, const float* W1, const float* W2,
                            const float* W3, unsigned short* wt) {
  __shared__ unsigned short T[64][72];
  int z = blockIdx.z, t = threadIdx.x;
  const float* W = (z == 0) ? W0 : (z == 1) ? W1 : (z == 2) ? W2 : W3;
  unsigned short* dst = wt + (size_t)z * WT_ONE;
  int k0 = blockIdx.y * 64, n0 = blockIdx.x * 64;
  #pragma unroll
  for (int i = 0; i < 4; i++) {
    int row = i * 16 + (t >> 4), col = 4 * (t & 15);
    float4 v = *(const float4*)&W[(size_t)(k0 + row) * DD + n0 + col];
    T[row][col + 0] = f2b(v.x); T[row][col + 1] = f2b(v.y);
    T[row][col + 2] = f2b(v.z); T[row][col + 3] = f2b(v.w);
  }
  __syncthreads();
  #pragma unroll
  for (int i = 0; i < 4; i++) {
    int n = i * 16 + (t >> 4), k = 4 * (t & 15);
    ushort4 o = make_ushort4(T[k][n], T[k + 1][n], T[k + 2][n], T[k + 3][n]);
    *(ushort4*)&dst[(size_t)(n0 + n) * DD + k0 + k] = o;
  }
}

// ---------------- GEMM: C = A @ Wt^T + bias ----------------
// MODE 0: A fp32 (q/k/v via blockIdx.z), write bf16 into (B,H,N,DH) head layout
// MODE 1: A bf16 (attn output x), write fp32 linear + bias
template <int MODE>
__global__ __launch_bounds__(256) void gemm_k(
    const void* A0, const void* A1, const void* A2,
    const unsigned short* Wt,
    const float* b0, const float* b1, const float* b2,
    unsigned short* dQ, unsigned short* dK, unsigned short* dV,
    float* out) {
  __shared__ unsigned short Al[128 * 40];   // [row][k] stride 40 (pad)
  __shared__ unsigned short Bl[128 * 40];   // [ncol][k] stride 40
  const int t = threadIdx.x, z = blockIdx.z;
  const int m0 = blockIdx.y * 128, n0 = blockIdx.x * 128;
  const unsigned short* Bsrc = Wt + (size_t)(MODE == 0 ? z : 3) * WT_ONE;
  const float* Af = (const float*)(z == 0 ? A0 : (z == 1 ? A1 : A2));
  const unsigned short* Ab = (const unsigned short*)A0;
  const float* bias = (MODE == 0) ? (z == 0 ? b0 : (z == 1 ? b1 : b2)) : b0;
  const int w = t >> 6, l = t & 63, lr = l & 15, lg = l >> 4;
  const int wm = (w >> 1) * 64, wn = (w & 1) * 64;

  f32x4 acc[4][4];
  #pragma unroll
  for (int i = 0; i < 4; i++)
    #pragma unroll
    for (int j = 0; j < 4; j++) acc[i][j] = (f32x4){0.f, 0.f, 0.f, 0.f};

  for (int k0 = 0; k0 < DD; k0 += 32) {
    __syncthreads();
    if (MODE == 0) {
      #pragma unroll
      for (int i = 0; i < 4; i++) {
        int row = i * 32 + (t >> 3), kk = 4 * (t & 7);
        float4 v = *(const float4*)&Af[(size_t)(m0 + row) * DD + k0 + kk];
        ushort4 o = make_ushort4(f2b(v.x), f2b(v.y), f2b(v.z), f2b(v.w));
        *(ushort4*)&Al[row * 40 + kk] = o;
      }
    } else {
      #pragma unroll
      for (int i = 0; i < 2; i++) {
        int row = i * 64 + (t >> 2), kk = 8 * (t & 3);
        *(uint4*)&Al[row * 40 + kk] =
            *(const uint4*)&Ab[(size_t)(m0 + row) * DD + k0 + kk];
      }
    }
    #pragma unroll
    for (int i = 0; i < 2; i++) {
      int row = i * 64 + (t >> 2), kk = 8 * (t & 3);
      *(uint4*)&Bl[row * 40 + kk] =
          *(const uint4*)&Bsrc[(size_t)(n0 + row) * DD + k0 + kk];
    }
    __syncthreads();
    bf16x8 af[4], bfr[4];
    #pragma unroll
    for (int mi = 0; mi < 4; mi++)
      af[mi] = *(const bf16x8*)&Al[(wm + mi * 16 + lr) * 40 + lg * 8];
    #pragma unroll
    for (int ni = 0; ni < 4; ni++)
      bfr[ni] = *(const bf16x8*)&Bl[(wn + ni * 16 + lr) * 40 + lg * 8];
    #pragma unroll
    for (int mi = 0; mi < 4; mi++)
      #pragma unroll
      for (int ni = 0; ni < 4; ni++)
        acc[mi][ni] = __builtin_amdgcn_mfma_f32_16x16x32_bf16(
            af[mi], bfr[ni], acc[mi][ni], 0, 0, 0);
  }

  unsigned short* dsts = (z == 0) ? dQ : (z == 1) ? dK : dV;
  #pragma unroll
  for (int mi = 0; mi < 4; mi++) {
    #pragma unroll
    for (int ni = 0; ni < 4; ni++) {
      int col = n0 + wn + ni * 16 + lr;
      float bv = bias[col];
      #pragma unroll
      for (int r = 0; r < 4; r++) {
        int m = m0 + wm + mi * 16 + lg * 4 + r;   // D row = (l>>4)*4+reg (verified)
        float val = acc[mi][ni][r] + bv;
        if (MODE == 0) {
          int b = m >> 11, n = m & 2047, h = col >> 6, dh = col & 63;
          dsts[(((size_t)(b * HH + h)) * NN + n) * DH + dh] = f2b(val);
        } else {
          out[(size_t)m * DD + col] = val;
        }
      }
    }
  }
}

// ---------------- vh (B,H,N,DH) -> vht (B,H,DH,N) ----------------
__global__ void transpose_vh(const unsigned short* vh, unsigned short* vht) {
  __shared__ unsigned short T[64][72];
  int t = threadIdx.x, n0 = blockIdx.x * 64;
  size_t bh = blockIdx.y;
  const unsigned short* src = vh + bh * (size_t)NN * DH;
  unsigned short* dst = vht + bh * (size_t)NN * DH;
  #pragma unroll
  for (int i = 0; i < 2; i++) {
    int row = i * 32 + (t >> 3), col = 8 * (t & 7);
    *(uint4*)&T[row][col] = *(const uint4*)&src[(size_t)(n0 + row) * DH + col];
  }
  __syncthreads();
  #pragma unroll
  for (int i = 0; i < 2; i++) {
    int dh = i * 32 + (t >> 3), nn = 8 * (t & 7);
    unsigned short o[8];
    #pragma unroll
    for (int j = 0; j < 8; j++) o[j] = T[nn + j][dh];
    *(uint4*)&dst[(size_t)dh * NN + n0 + nn] = *(const uint4*)o;
  }
}

// ---------------- flash attention ----------------
// grid (N/64, H, B), block 256 (4 waves x 16 q-rows). K-tile = 64.
__global__ __launch_bounds__(256) void attn_k(
    const unsigned short* qh, const unsigned short* kh,
    const unsigned short* vht, const unsigned long long* packed,
    unsigned short* x) {
  __shared__ unsigned short Kl[64 * 72];      // [kpos][dh]
  __shared__ unsigned short Vl[64 * 72];      // [dh][kpos]
  __shared__ unsigned short Pl[4][16 * 72];   // per-wave P strip [qlocal][kpos]
  const int t = threadIdx.x, w = t >> 6, l = t & 63;
  const int lr = l & 15, lg = l >> 4;
  const int q0 = blockIdx.x * 64, h = blockIdx.y, b = blockIdx.z;
  const size_t bh = (size_t)b * HH + h;
  const unsigned short* Q = qh + bh * (size_t)NN * DH;
  const unsigned short* K = kh + bh * (size_t)NN * DH;
  const unsigned short* V = vht + bh * (size_t)NN * DH;
  const unsigned long long* pm = packed + (size_t)b * NN * (NN / 64);

  bf16x8 qf[2];
  {
    int qrow = q0 + w * 16 + lr;               // A-frag row = l&15
    #pragma unroll
    for (int kc = 0; kc < 2; kc++)
      qf[kc] = *(const bf16x8*)&Q[(size_t)qrow * DH + kc * 32 + lg * 8];
  }

  f32x4 o[4];
  #pragma unroll
  for (int f = 0; f < 4; f++) o[f] = (f32x4){0.f, 0.f, 0.f, 0.f};
  float mrun[4] = {-1e30f, -1e30f, -1e30f, -1e30f};
  float lsum[4] = {0.f, 0.f, 0.f, 0.f};

  for (int kt = 0; kt < NN / 64; kt++) {
    __syncthreads();
    {   // stage K [64][64] and V^T [64][64] (both vector loads/stores)
      int row = t >> 2, cc = 16 * (t & 3);
      *(uint4*)&Kl[row * 72 + cc] =
          *(const uint4*)&K[(size_t)(kt * 64 + row) * DH + cc];
      *(uint4*)&Kl[row * 72 + cc + 8] =
          *(const uint4*)&K[(size_t)(kt * 64 + row) * DH + cc + 8];
      *(uint4*)&Vl[row * 72 + cc] =
          *(const uint4*)&V[(size_t)row * NN + kt * 64 + cc];
      *(uint4*)&Vl[row * 72 + cc + 8] =
          *(const uint4*)&V[(size_t)row * NN + kt * 64 + cc + 8];
    }
    __syncthreads();

    unsigned long long mw[4];
    #pragma unroll
    for (int r = 0; r < 4; r++)
      mw[r] = pm[(size_t)(q0 + w * 16 + lg * 4 + r) * (NN / 64) + kt];

    // S = Q K^T (rows of D = lg*4+r, cols = 16f+lr)
    f32x4 s[4];
    #pragma unroll
    for (int f = 0; f < 4; f++) {
      f32x4 sv = (f32x4){0.f, 0.f, 0.f, 0.f};
      #pragma unroll
      for (int kc = 0; kc < 2; kc++) {
        bf16x8 kf = *(const bf16x8*)&Kl[(16 * f + lr) * 72 + kc * 32 + lg * 8];
        sv = __builtin_amdgcn_mfma_f32_16x16x32_bf16(qf[kc], kf, sv, 0, 0, 0);
      }
      s[f] = sv;
    }

    // online softmax, wave-parallel (16-lane row groups)
    float pv[4][4];  // [f][r]
    float sf[4];
    #pragma unroll
    for (int r = 0; r < 4; r++) {
      float se[4], mx = -1e30f;
      #pragma unroll
      for (int f = 0; f < 4; f++) {
        int c = 16 * f + lr;
        bool msk = (mw[r] >> c) & 1ull;
        float vv = msk ? -1e30f : s[f][r] * SCALE;
        se[f] = vv;
        mx = fmaxf(mx, vv);
      }
      #pragma unroll
      for (int d = 1; d < 16; d <<= 1) mx = fmaxf(mx, __shfl_xor(mx, d));
      float mnew = fmaxf(mrun[r], mx);
      float rs = 0.f;
      #pragma unroll
      for (int f = 0; f < 4; f++) {
        float p = (se[f] <= -1e29f) ? 0.f : __expf(se[f] - mnew);
        pv[f][r] = p;
        rs += p;
      }
      #pragma unroll
      for (int d = 1; d < 16; d <<= 1) rs += __shfl_xor(rs, d);
      sf[r] = __expf(mrun[r] - mnew);
      lsum[r] = lsum[r] * sf[r] + rs;
      mrun[r] = mnew;
    }
    #pragma unroll
    for (int f = 0; f < 4; f++)
      #pragma unroll
      for (int r = 0; r < 4; r++) o[f][r] *= sf[r];

    // P -> LDS (to reach A-fragment layout), then PV
    #pragma unroll
    for (int f = 0; f < 4; f++)
      #pragma unroll
      for (int r = 0; r < 4; r++)
        Pl[w][(lg * 4 + r) * 72 + 16 * f + lr] = f2b(pv[f][r]);

    bf16x8 pf[2];
    #pragma unroll
    for (int kc = 0; kc < 2; kc++)
      pf[kc] = *(const bf16x8*)&Pl[w][lr * 72 + kc * 32 + lg * 8];
    #pragma unroll
    for (int f = 0; f < 4; f++)
      #pragma unroll
      for (int kc = 0; kc < 2; kc++) {
        bf16x8 vf = *(const bf16x8*)&Vl[(16 * f + lr) * 72 + kc * 32 + lg * 8];
        o[f] = __builtin_amdgcn_mfma_f32_16x16x32_bf16(pf[kc], vf, o[f], 0, 0, 0);
      }
  }

  #pragma unroll
  for (int r = 0; r < 4; r++) {
    float inv = 1.f / fmaxf(lsum[r], 1e-30f);
    int qrow = q0 + w * 16 + lg * 4 + r;
    #pragma unroll
    for (int f = 0; f < 4; f++) {
      float val = o[f][r] * inv;
      x[((size_t)b * NN + qrow) * DD + h * DH + 16 * f + lr] = f2b(val);
    }
  }
}

extern "C" void kernel_launch(void* const* d_in, const int* in_sizes, int n_in,
                              void* d_out, int out_size, void* d_ws, size_t ws_size,
                              hipStream_t stream) {
  const float* q  = (const float*)d_in[0];
  const float* k  = (const float*)d_in[1];
  const float* v  = (const float*)d_in[2];
  const void*  mk = d_in[3];
  const float* Wq = (const float*)d_in[4];
  const float* bq = (const float*)d_in[5];
  const float* Wk = (const float*)d_in[6];
  const float* bk = (const float*)d_in[7];
  const float* Wv = (const float*)d_in[8];
  const float* bv = (const float*)d_in[9];
  const float* Wp = (const float*)d_in[10];
  const float* bp = (const float*)d_in[11];
  float* out = (float*)d_out;
  char* ws = (char*)d_ws;

  unsigned int* flag = (unsigned int*)ws;
  unsigned long long* packed = (unsigned long long*)(ws + OFF_PACK);
  unsigned short* wt  = (unsigned short*)(ws + OFF_WT);
  unsigned short* qh  = (unsigned short*)(ws + OFF_QH);
  unsigned short* khp = (unsigned short*)(ws + OFF_KH);
  unsigned short* vh  = (unsigned short*)(ws + OFF_VH);
  unsigned short* vht = (unsigned short*)(ws + OFF_VT);
  unsigned short* x   = (unsigned short*)(ws + OFF_X);

  hipMemsetAsync(flag, 0, 4, stream);
  detect_mask<<<1, 256, 0, stream>>>((const unsigned int*)mk, flag);
  pack_mask<<<dim3(512), 256, 0, stream>>>(mk, flag, packed);
  transpose_w<<<dim3(16, 16, 4), 256, 0, stream>>>(Wq, Wk, Wv, Wp, wt);
  gemm_k<0><<<dim3(8, 32, 3), 256, 0, stream>>>(q, k, v, wt, bq, bk, bv,
                                                qh, khp, vh, nullptr);
  transpose_vh<<<dim3(32, 32), 256, 0, stream>>>(vh, vht);
  attn_k<<<dim3(32, 16, 2), 256, 0, stream>>>(qh, khp, vht, packed, x);
  gemm_k<1><<<dim3(8, 32, 1), 256, 0, stream>>>(x, nullptr, nullptr, wt, bp,
                                                nullptr, nullptr, nullptr,
                                                nullptr, nullptr, out);
}

// Round 2
// 217.824 us; speedup vs baseline: 1.1975x; 1.1975x over previous
//
#include <hip/hip_runtime.h>
#include <stdint.h>

typedef short bf16x8 __attribute__((ext_vector_type(8)));
typedef float f32x4 __attribute__((ext_vector_type(4)));

#define DEV __device__ __forceinline__

static constexpr int BB = 2, NN = 2048, DD = 1024, HH = 16, DH = 64;
static constexpr float SCALE = 0.125f; // DH^-0.5

// ---- workspace layout (bytes) ----
static constexpr size_t OFF_PACK   = 1024;
static constexpr size_t PACK_BYTES = (size_t)BB * NN * (NN / 64) * 8ull; // 1MB
static constexpr size_t OFF_WT     = OFF_PACK + PACK_BYTES;
static constexpr size_t WT_ONE     = (size_t)DD * DD;
static constexpr size_t HEAD_BYTES = (size_t)BB * HH * NN * DH * 2ull;   // 8MB
static constexpr size_t OFF_QH     = OFF_WT + 4 * WT_ONE * 2;
static constexpr size_t OFF_KH     = OFF_QH + HEAD_BYTES;
static constexpr size_t OFF_VT     = OFF_KH + HEAD_BYTES;
static constexpr size_t OFF_X      = OFF_VT + HEAD_BYTES;   // x (always); qb aliases (big path)
static constexpr size_t OFF_KB     = OFF_X + HEAD_BYTES;
static constexpr size_t OFF_VB     = OFF_KB + HEAD_BYTES;
static constexpr size_t NEED_BIG   = OFF_VB + HEAD_BYTES;   // ~59.8MB

DEV unsigned short f2b(float f) {                  // fp32 -> bf16 RNE
  unsigned int u = __builtin_bit_cast(unsigned int, f);
  u = (u + 0x7fffu + ((u >> 16) & 1u)) >> 16;
  return (unsigned short)u;
}

#define GLOAD16(gp, lp) __builtin_amdgcn_global_load_lds(                     \
    (const __attribute__((address_space(1))) void*)(gp),                      \
    (__attribute__((address_space(3))) void*)(lp), 16, 0, 0)

// ---------------- mask dtype detection ----------------
__global__ void detect_mask(const unsigned int* m, unsigned int* flag) {
  int t = threadIdx.x;
  uint4 v = ((const uint4*)m)[t];
  unsigned int vals[4] = {v.x, v.y, v.z, v.w};
  unsigned int f = 0;
  for (int i = 0; i < 4; i++) {
    unsigned int x = vals[i];
    if (x != 0u && x != 1u) f |= 1u;
    if (x != 0u && x != 0x3f800000u) f |= 2u;
  }
  if (f) atomicOr(flag, f);
}

// ---------------- mask packing: 1 bit per entry ----------------
__global__ void pack_mask(const void* msrc, const unsigned int* flag,
                          unsigned long long* packed) {
  int w = blockIdx.x * 256 + threadIdx.x;
  unsigned int f = *flag;
  size_t base = (size_t)(w >> 5) * 2048 + (size_t)(w & 31) * 64;
  unsigned long long bits = 0ull;
  if (!(f & 1u)) {                                 // int32 storage
    const int4* p = (const int4*)msrc + (base >> 2);
    #pragma unroll
    for (int c = 0; c < 16; c++) {
      int4 q = p[c];
      if (q.x) bits |= 1ull << (4 * c + 0);
      if (q.y) bits |= 1ull << (4 * c + 1);
      if (q.z) bits |= 1ull << (4 * c + 2);
      if (q.w) bits |= 1ull << (4 * c + 3);
    }
  } else if (!(f & 2u)) {                          // float32 storage
    const float4* p = (const float4*)msrc + (base >> 2);
    #pragma unroll
    for (int c = 0; c < 16; c++) {
      float4 q = p[c];
      if (q.x != 0.f) bits |= 1ull << (4 * c + 0);
      if (q.y != 0.f) bits |= 1ull << (4 * c + 1);
      if (q.z != 0.f) bits |= 1ull << (4 * c + 2);
      if (q.w != 0.f) bits |= 1ull << (4 * c + 3);
    }
  } else {                                         // uint8/bool storage
    const uint4* p = (const uint4*)((const char*)msrc + base);
    #pragma unroll
    for (int c = 0; c < 4; c++) {
      uint4 q = p[c];
      unsigned int vals[4] = {q.x, q.y, q.z, q.w};
      #pragma unroll
      for (int i = 0; i < 4; i++)
        #pragma unroll
        for (int j = 0; j < 4; j++)
          if ((vals[i] >> (8 * j)) & 0xffu) bits |= 1ull << (16 * c + 4 * i + j);
    }
  }
  packed[w] = bits;
}

// ---------------- weight transpose: W[k][n] f32 -> Wt[n][k] bf16 ----------------
__global__ void transpose_w(const float* W0, const float* W1, const float* W2,
                            const float* W3, unsigned short* wt) {
  __shared__ unsigned short T[64][72];
  int z = blockIdx.z, t = threadIdx.x;
  const float* W = (z == 0) ? W0 : (z == 1) ? W1 : (z == 2) ? W2 : W3;
  unsigned short* dst = wt + (size_t)z * WT_ONE;
  int k0 = blockIdx.y * 64, n0 = blockIdx.x * 64;
  #pragma unroll
  for (int i = 0; i < 4; i++) {
    int row = i * 16 + (t >> 4), col = 4 * (t & 15);
    float4 v = *(const float4*)&W[(size_t)(k0 + row) * DD + n0 + col];
    T[row][col + 0] = f2b(v.x); T[row][col + 1] = f2b(v.y);
    T[row][col + 2] = f2b(v.z); T[row][col + 3] = f2b(v.w);
  }
  __syncthreads();
  #pragma unroll
  for (int i = 0; i < 4; i++) {
    int n = i * 16 + (t >> 4), k = 4 * (t & 15);
    ushort4 o = make_ushort4(T[k][n], T[k + 1][n], T[k + 2][n], T[k + 3][n]);
    *(ushort4*)&dst[(size_t)(n0 + n) * DD + k0 + k] = o;
  }
}

// ---------------- fp32 -> bf16 convert for q,k,v ----------------
__global__ void cvt_qkv(const float* q, const float* k, const float* v,
                        unsigned short* qb, unsigned short* kb,
                        unsigned short* vb) {
  int z = blockIdx.z;
  const float* s = (z == 0) ? q : (z == 1) ? k : v;
  unsigned short* d = (z == 0) ? qb : (z == 1) ? kb : vb;
  size_t i = ((size_t)blockIdx.x * 256 + threadIdx.x) * 8;
  float4 a = *(const float4*)&s[i];
  float4 b2 = *(const float4*)&s[i + 4];
  unsigned short o[8] = {f2b(a.x),  f2b(a.y),  f2b(a.z),  f2b(a.w),
                         f2b(b2.x), f2b(b2.y), f2b(b2.z), f2b(b2.w)};
  *(uint4*)&d[i] = *(const uint4*)o;
}

// ---------------- QKV projection GEMM (m97 structure) ----------------
template <int AFP32>
__global__ __launch_bounds__(256) void gemm_qkv(
    const void* A0, const void* A1, const void* A2,
    const unsigned short* Wt,
    const float* b0, const float* b1, const float* b2,
    unsigned short* dQ, unsigned short* dK, unsigned short* dVt) {
  __shared__ unsigned short Al[128 * 32];
  __shared__ unsigned short Bl[128 * 32];
  const int t = threadIdx.x, z = blockIdx.z;
  const int m0 = blockIdx.y * 128, n0 = blockIdx.x * 128;
  const unsigned short* Bsrc = Wt + (size_t)z * WT_ONE;
  const void* Av = (z == 0) ? A0 : (z == 1) ? A1 : A2;
  const float* bias = (z == 0) ? b0 : (z == 1) ? b1 : b2;
  const int w = t >> 6, l = t & 63, lr = l & 15, lg = l >> 4;
  const int wm = (w >> 1) * 64, wn = (w & 1) * 64;

  f32x4 acc[4][4];
  #pragma unroll
  for (int i = 0; i < 4; i++)
    #pragma unroll
    for (int j = 0; j < 4; j++) acc[i][j] = (f32x4){0.f, 0.f, 0.f, 0.f};

  for (int k0 = 0; k0 < DD; k0 += 32) {
    __syncthreads();
    if (AFP32) {
      const float* Af = (const float*)Av;
      #pragma unroll
      for (int i = 0; i < 4; i++) {
        int row = i * 32 + (t >> 3), kk = 4 * (t & 7);
        float4 vv = *(const float4*)&Af[(size_t)(m0 + row) * DD + k0 + kk];
        ushort4 o4 = make_ushort4(f2b(vv.x), f2b(vv.y), f2b(vv.z), f2b(vv.w));
        *(ushort4*)&Al[row * 32 + kk] = o4;
      }
    } else {
      const unsigned short* Ab = (const unsigned short*)Av;
      #pragma unroll
      for (int c = 0; c < 2; c++)
        GLOAD16(&Ab[(size_t)(m0 + w * 32 + c * 16 + (l >> 2)) * DD + k0 + (l & 3) * 8],
                &Al[(w * 32 + c * 16) * 32]);
    }
    #pragma unroll
    for (int c = 0; c < 2; c++)
      GLOAD16(&Bsrc[(size_t)(n0 + w * 32 + c * 16 + (l >> 2)) * DD + k0 + (l & 3) * 8],
              &Bl[(w * 32 + c * 16) * 32]);
    __syncthreads();

    bf16x8 af[4], bfr[4];
    #pragma unroll
    for (int mi = 0; mi < 4; mi++)
      af[mi] = *(const bf16x8*)&Al[(wm + mi * 16 + lr) * 32 + lg * 8];
    #pragma unroll
    for (int ni = 0; ni < 4; ni++)
      bfr[ni] = *(const bf16x8*)&Bl[(wn + ni * 16 + lr) * 32 + lg * 8];
    #pragma unroll
    for (int mi = 0; mi < 4; mi++)
      #pragma unroll
      for (int ni = 0; ni < 4; ni++)
        acc[mi][ni] = __builtin_amdgcn_mfma_f32_16x16x32_bf16(
            af[mi], bfr[ni], acc[mi][ni], 0, 0, 0);
  }

  #pragma unroll
  for (int mi = 0; mi < 4; mi++) {
    #pragma unroll
    for (int ni = 0; ni < 4; ni++) {
      int col = n0 + wn + ni * 16 + lr;
      float bv = bias[col];
      int h = col >> 6, dh = col & 63;
      int mbase = m0 + wm + mi * 16 + lg * 4;
      if (z == 2) {
        int bq = mbase >> 11, n = mbase & 2047;
        unsigned short o4[4];
        #pragma unroll
        for (int r = 0; r < 4; r++) o4[r] = f2b(acc[mi][ni][r] + bv);
        *(ushort4*)&dVt[(((size_t)(bq * HH + h)) * DH + dh) * NN + n] =
            *(const ushort4*)o4;
      } else {
        unsigned short* dst = (z == 0) ? dQ : dK;
        #pragma unroll
        for (int r = 0; r < 4; r++) {
          int m = mbase + r;
          int bq = m >> 11, n = m & 2047;
          dst[(((size_t)(bq * HH + h)) * NN + n) * DH + dh] =
              f2b(acc[mi][ni][r] + bv);
        }
      }
    }
  }
}

// ---------------- output projection GEMM ----------------
__global__ __launch_bounds__(256) void gemm_proj(
    const unsigned short* X, const unsigned short* Wt, const float* bias,
    float* out) {
  __shared__ unsigned short Al[128 * 32];
  __shared__ unsigned short Bl[128 * 32];
  const int t = threadIdx.x;
  const int m0 = blockIdx.y * 128, n0 = blockIdx.x * 128;
  const int w = t >> 6, l = t & 63, lr = l & 15, lg = l >> 4;
  const int wm = (w >> 1) * 64, wn = (w & 1) * 64;

  f32x4 acc[4][4];
  #pragma unroll
  for (int i = 0; i < 4; i++)
    #pragma unroll
    for (int j = 0; j < 4; j++) acc[i][j] = (f32x4){0.f, 0.f, 0.f, 0.f};

  for (int k0 = 0; k0 < DD; k0 += 32) {
    __syncthreads();
    #pragma unroll
    for (int c = 0; c < 2; c++) {
      GLOAD16(&X[(size_t)(m0 + w * 32 + c * 16 + (l >> 2)) * DD + k0 + (l & 3) * 8],
              &Al[(w * 32 + c * 16) * 32]);
      GLOAD16(&Wt[(size_t)(n0 + w * 32 + c * 16 + (l >> 2)) * DD + k0 + (l & 3) * 8],
              &Bl[(w * 32 + c * 16) * 32]);
    }
    __syncthreads();

    bf16x8 af[4], bfr[4];
    #pragma unroll
    for (int mi = 0; mi < 4; mi++)
      af[mi] = *(const bf16x8*)&Al[(wm + mi * 16 + lr) * 32 + lg * 8];
    #pragma unroll
    for (int ni = 0; ni < 4; ni++)
      bfr[ni] = *(const bf16x8*)&Bl[(wn + ni * 16 + lr) * 32 + lg * 8];
    #pragma unroll
    for (int mi = 0; mi < 4; mi++)
      #pragma unroll
      for (int ni = 0; ni < 4; ni++)
        acc[mi][ni] = __builtin_amdgcn_mfma_f32_16x16x32_bf16(
            af[mi], bfr[ni], acc[mi][ni], 0, 0, 0);
  }

  #pragma unroll
  for (int mi = 0; mi < 4; mi++) {
    #pragma unroll
    for (int ni = 0; ni < 4; ni++) {
      int col = n0 + wn + ni * 16 + lr;
      float bv = bias[col];
      #pragma unroll
      for (int r = 0; r < 4; r++) {
        int m = m0 + wm + mi * 16 + lg * 4 + r;
        out[(size_t)m * DD + col] = acc[mi][ni][r] + bv;
      }
    }
  }
}

// ---------------- flash attention (swapped-operand QK^T) ----------------
__global__ __launch_bounds__(256) void attn_k(
    const unsigned short* qh, const unsigned short* kh,
    const unsigned short* vht, const unsigned long long* packed,
    unsigned short* x) {
  __shared__ unsigned short Kl[64 * 72];      // [kpos][dh]
  __shared__ unsigned short Vl[64 * 72];      // [dh][kpos]
  __shared__ unsigned short Pl[4][16 * 72];   // per-wave P [q][kpos]
  const int t = threadIdx.x, w = t >> 6, l = t & 63;
  const int lr = l & 15, lg = l >> 4;
  const int q0 = blockIdx.x * 64, h = blockIdx.y, b = blockIdx.z;
  const size_t bh = (size_t)b * HH + h;
  const unsigned short* Q = qh + bh * (size_t)NN * DH;
  const unsigned short* K = kh + bh * (size_t)NN * DH;
  const unsigned short* V = vht + bh * (size_t)NN * DH;  // [dh][n]
  const int qrow = q0 + w * 16 + lr;
  const unsigned long long* pmrow =
      packed + ((size_t)b * NN + qrow) * (NN / 64);

  bf16x8 qf[2];
  #pragma unroll
  for (int kc = 0; kc < 2; kc++)
    qf[kc] = *(const bf16x8*)&Q[(size_t)qrow * DH + kc * 32 + lg * 8];

  f32x4 o[4];
  #pragma unroll
  for (int f = 0; f < 4; f++) o[f] = (f32x4){0.f, 0.f, 0.f, 0.f};
  float mrun = -1e30f, lsum = 0.f;

  const int srow = t >> 2, scol = (t & 3) * 16;
  uint4 k0r, k1r, v0r, v1r;
  {
    const unsigned short* kp = &K[(size_t)srow * DH + scol];
    const unsigned short* vp = &V[(size_t)srow * NN + scol];
    k0r = *(const uint4*)kp;  k1r = *(const uint4*)(kp + 8);
    v0r = *(const uint4*)vp;  v1r = *(const uint4*)(vp + 8);
  }

  for (int kt = 0; kt < NN / 64; kt++) {
    __syncthreads();
    *(uint4*)&Kl[srow * 72 + scol]     = k0r;
    *(uint4*)&Kl[srow * 72 + scol + 8] = k1r;
    *(uint4*)&Vl[srow * 72 + scol]     = v0r;
    *(uint4*)&Vl[srow * 72 + scol + 8] = v1r;
    __syncthreads();
    if (kt + 1 < NN / 64) {
      const unsigned short* kp = &K[(size_t)((kt + 1) * 64 + srow) * DH + scol];
      const unsigned short* vp = &V[(size_t)srow * NN + (kt + 1) * 64 + scol];
      k0r = *(const uint4*)kp;  k1r = *(const uint4*)(kp + 8);
      v0r = *(const uint4*)vp;  v1r = *(const uint4*)(vp + 8);
    }

    unsigned long long mw = pmrow[kt];

    f32x4 sv[4];
    #pragma unroll
    for (int f = 0; f < 4; f++) {
      f32x4 s = (f32x4){0.f, 0.f, 0.f, 0.f};
      #pragma unroll
      for (int kc = 0; kc < 2; kc++) {
        bf16x8 kf = *(const bf16x8*)&Kl[(16 * f + lr) * 72 + kc * 32 + lg * 8];
        s = __builtin_amdgcn_mfma_f32_16x16x32_bf16(kf, qf[kc], s, 0, 0, 0);
      }
      sv[f] = s;
    }

    float su[4][4];
    float mx = -1e30f;
    #pragma unroll
    for (int f = 0; f < 4; f++)
      #pragma unroll
      for (int r = 0; r < 4; r++) {
        int kbit = 16 * f + lg * 4 + r;
        bool msk = (mw >> kbit) & 1ull;
        float vv = msk ? -1e30f : sv[f][r] * SCALE;
        su[f][r] = vv;
        mx = fmaxf(mx, vv);
      }
    mx = fmaxf(mx, __shfl_xor(mx, 16));
    mx = fmaxf(mx, __shfl_xor(mx, 32));

    float mnew = fmaxf(mrun, mx);
    float sf = __expf(mrun - mnew);
    float rs = 0.f;
    float p[4][4];
    #pragma unroll
    for (int f = 0; f < 4; f++)
      #pragma unroll
      for (int r = 0; r < 4; r++) {
        float pv = (su[f][r] <= -1e29f) ? 0.f : __expf(su[f][r] - mnew);
        p[f][r] = pv;
        rs += pv;
      }
    rs += __shfl_xor(rs, 16);
    rs += __shfl_xor(rs, 32);
    lsum = lsum * sf + rs;
    mrun = mnew;
    #pragma unroll
    for (int f = 0; f < 4; f++) o[f] *= sf;

    #pragma unroll
    for (int f = 0; f < 4; f++) {
      unsigned short pk[4] = {f2b(p[f][0]), f2b(p[f][1]), f2b(p[f][2]),
                              f2b(p[f][3])};
      *(ushort4*)&Pl[w][lr * 72 + 16 * f + lg * 4] = *(const ushort4*)pk;
    }
    asm volatile("s_waitcnt lgkmcnt(0)" ::: "memory");

    bf16x8 pf0 = *(const bf16x8*)&Pl[w][lr * 72 + 0  + lg * 8];
    bf16x8 pf1 = *(const bf16x8*)&Pl[w][lr * 72 + 32 + lg * 8];
    #pragma unroll
    for (int f = 0; f < 4; f++) {
      bf16x8 vf0 = *(const bf16x8*)&Vl[(16 * f + lr) * 72 + 0  + lg * 8];
      o[f] = __builtin_amdgcn_mfma_f32_16x16x32_bf16(vf0, pf0, o[f], 0, 0, 0);
      bf16x8 vf1 = *(const bf16x8*)&Vl[(16 * f + lr) * 72 + 32 + lg * 8];
      o[f] = __builtin_amdgcn_mfma_f32_16x16x32_bf16(vf1, pf1, o[f], 0, 0, 0);
    }
  }

  float inv = 1.f / fmaxf(lsum, 1e-30f);
  #pragma unroll
  for (int f = 0; f < 4; f++) {
    unsigned short ov[4];
    #pragma unroll
    for (int r = 0; r < 4; r++) ov[r] = f2b(o[f][r] * inv);
    *(ushort4*)&x[((size_t)b * NN + qrow) * DD + h * DH + 16 * f + lg * 4] =
        *(const ushort4*)ov;
  }
}

extern "C" void kernel_launch(void* const* d_in, const int* in_sizes, int n_in,
                              void* d_out, int out_size, void* d_ws, size_t ws_size,
                              hipStream_t stream) {
  const float* q  = (const float*)d_in[0];
  const float* k  = (const float*)d_in[1];
  const float* v  = (const float*)d_in[2];
  const void*  mk = d_in[3];
  const float* Wq = (const float*)d_in[4];
  const float* bq = (const float*)d_in[5];
  const float* Wk = (const float*)d_in[6];
  const float* bk = (const float*)d_in[7];
  const float* Wv = (const float*)d_in[8];
  const float* bv = (const float*)d_in[9];
  const float* Wp = (const float*)d_in[10];
  const float* bp = (const float*)d_in[11];
  float* out = (float*)d_out;
  char* ws = (char*)d_ws;

  unsigned int* flag = (unsigned int*)ws;
  unsigned long long* packed = (unsigned long long*)(ws + OFF_PACK);
  unsigned short* wt  = (unsigned short*)(ws + OFF_WT);
  unsigned short* qhp = (unsigned short*)(ws + OFF_QH);
  unsigned short* khp = (unsigned short*)(ws + OFF_KH);
  unsigned short* vht = (unsigned short*)(ws + OFF_VT);
  unsigned short* x   = (unsigned short*)(ws + OFF_X);
  unsigned short* qb  = (unsigned short*)(ws + OFF_X);  // alias: dead before attn
  unsigned short* kb  = (unsigned short*)(ws + OFF_KB);
  unsigned short* vb  = (unsigned short*)(ws + OFF_VB);

  const bool big = ws_size >= NEED_BIG;

  hipMemsetAsync(flag, 0, 4, stream);
  detect_mask<<<1, 256, 0, stream>>>((const unsigned int*)mk, flag);
  pack_mask<<<dim3(512), 256, 0, stream>>>(mk, flag, packed);
  transpose_w<<<dim3(16, 16, 4), 256, 0, stream>>>(Wq, Wk, Wv, Wp, wt);
  if (big) {
    cvt_qkv<<<dim3(2048, 1, 3), 256, 0, stream>>>(q, k, v, qb, kb, vb);
    gemm_qkv<0><<<dim3(8, 32, 3), 256, 0, stream>>>(qb, kb, vb, wt, bq, bk, bv,
                                                    qhp, khp, vht);
  } else {
    gemm_qkv<1><<<dim3(8, 32, 3), 256, 0, stream>>>(q, k, v, wt, bq, bk, bv,
                                                    qhp, khp, vht);
  }
  attn_k<<<dim3(32, 16, 2), 256, 0, stream>>>(qhp, khp, vht, packed, x);
  gemm_proj<<<dim3(8, 32), 256, 0, stream>>>(x, wt + 3 * WT_ONE, bp, out);
}